// Round 1
// baseline (551.911 us; speedup 1.0000x reference)
//
#include <hip/hip_runtime.h>

// IndexedConv: out[n,o,l] = bias[o] + sum_{c,k} x[n,c,idx[k,l]] * w[o,c,k]
// N=16, C_IN=32, C_OUT=128, K=7, L=40000.
//
// xt[l][n*32+c] bf16 -> each gather (k,l) is one contiguous 1KB row; per-l
// compute is 16x128x224 GEMM via mfma_f32_16x16x32_bf16. fp32 acc/output.
//
// R2: full k-unroll + idx prefetch (one b ahead) + branch-free gathers.
// R3: LDS-staged epilogue. R2's 16B/lane stores put each 64B out-line's four
//     sectors in four different waves; L2 temporal merging was probabilistic
//     (R1: 1.98x write amp). Now each t's 16l x 16n x 16o tile is staged in
//     LDS (XOR-swizzled, 2-way conflicts = free) and each THREAD writes one
//     full 64B line as 4 consecutive dwordx4 -> guaranteed 1.0x write amp.
//     Barriers are raw s_barrier + lgkmcnt(0) only (no vmcnt drain: idx
//     prefetch and prior-t stores stay in flight).

#define L_TOT 40000
#define NC 512          // N*C_IN = 16*32
#define NBATCH 2500     // L_TOT / 16 (16 l per block-batch)

typedef __bf16 bf16x8 __attribute__((ext_vector_type(8)));
typedef float float4_t __attribute__((ext_vector_type(4)));
typedef int int4v __attribute__((ext_vector_type(4)));

// ---------------------------------------------------------------- indices ---
__global__ void repack_idx(const int* __restrict__ raw, int* __restrict__ idx32) {
    __shared__ unsigned long long votes[4];
    int tid = threadIdx.x;
    int wprobe = raw[2 * tid + 1];            // first 512 ints exist either way
    bool ok = (wprobe == 0) || (wprobe == -1);
    unsigned long long vote = __ballot(ok);
    if ((tid & 63) == 0) votes[tid >> 6] = vote;
    __syncthreads();
    bool is64 = ((votes[0] & votes[1] & votes[2] & votes[3]) == ~0ull);
    int i = blockIdx.x * 256 + tid;
    if (i < 7 * L_TOT) {
        if (is64) idx32[i] = raw[2 * i];      // low word of little-endian int64
        else      idx32[i] = raw[i];
    }
}

// -------------------------------------------------------------- transpose ---
__global__ void transpose_cast(const float* __restrict__ x, __bf16* __restrict__ xt) {
    __shared__ float tile[32][66];
    int l0  = blockIdx.x * 64;
    int nc0 = blockIdx.y * 32;
    int tid = threadIdx.x;
    int lloc = tid & 63, sub = tid >> 6;
#pragma unroll
    for (int i = 0; i < 8; ++i) {
        int nc = i * 4 + sub;
        tile[nc][lloc] = x[(size_t)(nc0 + nc) * L_TOT + l0 + lloc];
    }
    __syncthreads();
    int ll = tid >> 2, g = tid & 3;
    bf16x8 v;
#pragma unroll
    for (int j = 0; j < 8; ++j) v[j] = (__bf16)tile[g * 8 + j][ll];
    *reinterpret_cast<bf16x8*>(xt + (size_t)(l0 + ll) * NC + nc0 + g * 8) = v;
}

// ----------------------------------------------------------------- pack W ---
// B-fragment layout: o = lane&15, c = (lane>>4)*8 + j, one frag per (k, o-tile).
__global__ void pack_w(const float* __restrict__ w, bf16x8* __restrict__ wp) {
    int gid = blockIdx.x * 256 + threadIdx.x;     // 0..3583
    if (gid >= 7 * 8 * 64) return;
    int k = gid >> 9, r = gid & 511, t = r >> 6, lane = r & 63;
    int col = lane & 15, quad = lane >> 4;
    int o = t * 16 + col;
    bf16x8 v;
#pragma unroll
    for (int j = 0; j < 8; ++j) {
        int c = quad * 8 + j;
        v[j] = (__bf16)w[(o * 32 + c) * 7 + k];
    }
    wp[gid] = v;
}

// ------------------------------------------------------------------- main ---
__launch_bounds__(256, 2)
__global__ void indexed_conv_main(const __bf16* __restrict__ xt,
                                  const bf16x8* __restrict__ wp,
                                  const float* __restrict__ bias,
                                  const int* __restrict__ idx,
                                  float* __restrict__ out) {
    __shared__ bf16x8 ldsW[3584];                 // 57,344 B
    __shared__ float4_t stg[1024];                // 16,384 B output staging
    int tid = threadIdx.x;
    for (int i = tid; i < 3584; i += 256) ldsW[i] = wp[i];

    int wave = tid >> 6, lane = tid & 63;
    int col = lane & 15, quad = lane >> 4;
    float bv[8];
#pragma unroll
    for (int t = 0; t < 8; ++t) bv[t] = bias[t * 16 + col];

    bf16x8 zero;
#pragma unroll
    for (int j = 0; j < 8; ++j) zero[j] = (__bf16)0.0f;

    __syncthreads();

    // A-fragment lane offset within a 512-elem xt row, in 16B units:
    // element (m*32 + quad*8), m = lane&15  ->  /8 = col*4 + quad
    int aoff = col * 4 + quad;

    // Epilogue read-side constants: thread owns output line (n,o) = (tid>>4, tid&15)
    int rs = (tid >> 2) & 3;                      // read-side XOR swizzle key

    int b = blockIdx.x;
    int4v idxc[7];
    if (b < NBATCH) {
        int l0 = b * 16 + wave * 4;
#pragma unroll
        for (int k = 0; k < 7; ++k)
            idxc[k] = *reinterpret_cast<const int4v*>(idx + k * L_TOT + l0);
    }

    for (; b < NBATCH; b += gridDim.x) {
        // Prefetch next iteration's indices now (consumed one full b later).
        int bn = b + gridDim.x;
        int4v idxn[7];
        if (bn < NBATCH) {
            int l0n = bn * 16 + wave * 4;
#pragma unroll
            for (int k = 0; k < 7; ++k)
                idxn[k] = *reinterpret_cast<const int4v*>(idx + k * L_TOT + l0n);
        }

        float4_t acc[4][8];
#pragma unroll
        for (int li = 0; li < 4; ++li)
#pragma unroll
            for (int t = 0; t < 8; ++t)
                acc[li][t] = (float4_t){bv[t], bv[t], bv[t], bv[t]};

#pragma unroll
        for (int k = 0; k < 7; ++k) {
            bf16x8 a[4];
#pragma unroll
            for (int li = 0; li < 4; ++li) {
                int v = idxc[k][li];
                int s = v < 0 ? 0 : v;                 // safe row
                const bf16x8* row =
                    reinterpret_cast<const bf16x8*>(xt + (size_t)s * NC);
                bf16x8 g = row[aoff];                  // unconditional issue
                a[li] = (v < 0) ? zero : g;            // cndmask, no branch
            }
#pragma unroll
            for (int t = 0; t < 8; ++t) {
                bf16x8 bw = ldsW[(k * 8 + t) * 64 + lane];
#pragma unroll
                for (int li = 0; li < 4; ++li)
                    acc[li][t] = __builtin_amdgcn_mfma_f32_16x16x32_bf16(
                        a[li], bw, acc[li][t], 0, 0, 0);
            }
        }

        // ---- LDS-staged epilogue: per t, redistribute so each thread owns
        // one full (n,o) 64B line (16 consecutive l) and writes it whole.
        // Raw s_barrier + lgkmcnt(0) only: no vmcnt drain, prefetched idxn
        // loads and previous t's global stores stay in flight.
        int lb = b * 16;
#pragma unroll
        for (int t = 0; t < 8; ++t) {
            // protect stg from previous t's (or previous b's) readers
            asm volatile("s_waitcnt lgkmcnt(0)" ::: "memory");
            __builtin_amdgcn_s_barrier();
#pragma unroll
            for (int reg = 0; reg < 4; ++reg) {
                int line = (quad * 4 + reg) * 16 + col;      // n*16 + o_local
                float4_t v = {acc[0][t][reg], acc[1][t][reg],
                              acc[2][t][reg], acc[3][t][reg]};
                // slot holds l-group `wave`; XOR swizzle -> 2-way banks (free)
                stg[line * 4 + (wave ^ ((line >> 2) & 3))] = v;
            }
            asm volatile("s_waitcnt lgkmcnt(0)" ::: "memory");
            __builtin_amdgcn_s_barrier();
            {
                float* obase = out +
                    (size_t)((tid >> 4) * 128 + t * 16 + (tid & 15)) * L_TOT + lb;
#pragma unroll
                for (int g = 0; g < 4; ++g) {
                    float4_t v = stg[tid * 4 + (g ^ rs)];    // l-group g
                    *reinterpret_cast<float4_t*>(obase + g * 4) = v;
                }
            }
        }

#pragma unroll
        for (int k = 0; k < 7; ++k) idxc[k] = idxn[k];
    }
}

// ----------------------------------------------------------------- launch ---
extern "C" void kernel_launch(void* const* d_in, const int* in_sizes, int n_in,
                              void* d_out, int out_size, void* d_ws, size_t ws_size,
                              hipStream_t stream) {
    const float* x    = (const float*)d_in[0];
    const float* w    = (const float*)d_in[1];
    const float* bias = (const float*)d_in[2];
    const int*   raw  = (const int*)d_in[3];
    float* out = (float*)d_out;

    char* ws = (char*)d_ws;
    __bf16* xt   = (__bf16*)(ws);                    // 40000*512*2 = 40,960,000 B
    bf16x8* wpck = (bf16x8*)(ws + 40960000);         //               57,344 B
    int*    idx32 = (int*)(ws + 41017344);           //            1,120,000 B

    repack_idx<<<(7 * L_TOT + 255) / 256, 256, 0, stream>>>(raw, idx32);
    transpose_cast<<<dim3(L_TOT / 64, NC / 32), 256, 0, stream>>>(x, xt);
    pack_w<<<14, 256, 0, stream>>>(w, wpck);
    indexed_conv_main<<<512, 256, 0, stream>>>(xt, wpck, bias, idx32, out);
}